// Round 2
// 1307.374 us; speedup vs baseline: 1.7459x; 1.7459x over previous
//
#include <hip/hip_runtime.h>

#define Cn 16
#define Dn 96
#define Sn (Dn*Dn*Dn)        /* 884736 */
#define DSTRIDE (Dn*Dn)      /* 9216 */
#define ENC_NEG_INF 0x007FFFFFu
#define HROW 68              /* f16 row stride: 136 B, bank stride 34%32=2 -> uniform */

typedef float v2f __attribute__((ext_vector_type(2)));
typedef float v4f __attribute__((ext_vector_type(4)));
typedef _Float16 v4h __attribute__((ext_vector_type(4)));

__device__ __forceinline__ v2f ld2(const float* p){
    v2f r; __builtin_memcpy(&r, p, 8); return r;
}
// monotonic float<->uint map for atomicMax on signed floats
__device__ __forceinline__ unsigned encf(float f){
    unsigned u = __float_as_uint(f);
    return (u & 0x80000000u) ? ~u : (u | 0x80000000u);
}
__device__ __forceinline__ float decf(unsigned u){
    return (u & 0x80000000u) ? __uint_as_float(u ^ 0x80000000u) : __uint_as_float(~u);
}
// tanh(x) = 1 - 2/(exp(2x)+1)
__device__ __forceinline__ float ftanh(float x){
    float t = __expf(2.0f*x);
    return 1.0f - __fdividef(2.0f, t + 1.0f);
}
__device__ __forceinline__ int clampi(int v){ return v<0?0:(v>Dn-1?Dn-1:v); }

__global__ void init_kernel(unsigned* __restrict__ maxv){
    if (threadIdx.x < 16) maxv[threadIdx.x] = ENC_NEG_INF;
}

// Stencil weight reorder (once):
//  wpT[t*48+q*16+c]=wp[(3c+q)*27+t]; bpP[q*16+c]=bp[3c+q]
__global__ void tr_kernel(const float* __restrict__ wp, const float* __restrict__ bp,
                          float* __restrict__ wpT, float* __restrict__ bpP){
    const int i = blockIdx.x*256 + threadIdx.x;
    if (i < 1296){ const int t=i/48, r=i%48, q=r>>4, c=r&15; wpT[i] = wp[(3*c+q)*27 + t]; }
    if (i < 48)  { const int q=i>>4, c=i&15; bpP[i] = bp[3*c + q]; }
}

// Pack MLP weights into v_mfma_f32_16x16x16_f16 B-fragment order, SPLIT into
// hi = f16(w), lo = f16(w - hi)  (3-term split-f16 GEMM gives ~fp32 accuracy).
// B-frag (nt,ks): lane l, elem e holds B[k=ks*16+(l>>4)*4+e][n=nt*16+(l&15)].
// Layer1 k runs over the PERMUTED dwconv index j=q*16+c  (orig = 3c+q).
__global__ void pack_kernel(const float* __restrict__ w1, const float* __restrict__ w2,
                            const float* __restrict__ w3,
                            _Float16* __restrict__ w1Fh, _Float16* __restrict__ w1Fl,
                            _Float16* __restrict__ w2Fh, _Float16* __restrict__ w2Fl,
                            _Float16* __restrict__ w3Fh, _Float16* __restrict__ w3Fl){
    const int i = blockIdx.x*256 + threadIdx.x;
    if (i < 3072){ // w1: [48 x 64], 4 nt * 3 ks tiles
        const int e = i & 3, l = (i>>2) & 63, t = i >> 8;   // t = nt*3+ks
        const int ks = t % 3, nt = t / 3;
        const int k = ks*16 + ((l>>4)<<2) + e;              // permuted j
        const int n = nt*16 + (l & 15);
        const int c = k & 15, q = k >> 4;
        const float v = w1[n*48 + 3*c + q];
        const _Float16 hh = (_Float16)v;
        w1Fh[i] = hh; w1Fl[i] = (_Float16)(v - (float)hh);
    }
    if (i < 4096){ // w2: [64 x 64], 4 nt * 4 ks tiles
        const int e = i & 3, l = (i>>2) & 63, t = i >> 8;   // t = nt*4+ks
        const int ks = t & 3, nt = t >> 2;
        const int k = ks*16 + ((l>>4)<<2) + e;
        const int n = nt*16 + (l & 15);
        const float v = w2[n*64 + k];
        const _Float16 hh = (_Float16)v;
        w2Fh[i] = hh; w2Fl[i] = (_Float16)(v - (float)hh);
    }
    if (i < 1024){ // w3: [64 x 16], 1 nt * 4 ks tiles
        const int e = i & 3, l = (i>>2) & 63, ks = i >> 8;
        const int k = ks*16 + ((l>>4)<<2) + e;
        const int n = l & 15;
        const float v = w3[n*64 + k];
        const _Float16 hh = (_Float16)v;
        w3Fh[i] = hh; w3Fl[i] = (_Float16)(v - (float)hh);
    }
}

// global max of x0 ch3 -> slot (pre-max for step 0; initial mask is all-ones)
__global__ __launch_bounds__(256) void prep_kernel(const float* __restrict__ x3,
    float* __restrict__ maskA, unsigned* __restrict__ slot)
{
    const int idx = blockIdx.x*256 + threadIdx.x;
    maskA[idx] = 1.0f;
    float v = x3[idx];
    #pragma unroll
    for (int o=32;o;o>>=1) v = fmaxf(v, __shfl_down(v, o));
    __shared__ float red[4];
    const int lane = threadIdx.x & 63, wid = threadIdx.x >> 6;
    if (lane==0) red[wid]=v;
    __syncthreads();
    if (threadIdx.x==0){
        float m = fmaxf(fmaxf(red[0],red[1]), fmaxf(red[2],red[3]));
        atomicMax(slot, encf(m));
    }
}

struct XBuf { float x[16]; float m; int v; };

__device__ __forceinline__ void prefetch_t(int t, int d, int h, int w,
    const float* __restrict__ xin, const float* __restrict__ min_, XBuf& B)
{
    const int zz = d + t/9 - 1;
    const int yy = h + (t/3)%3 - 1;
    const int xx = w + t%3 - 1;
    const int zc = clampi(zz), yc = clampi(yy), xc = clampi(xx);
    B.v = (zz==zc) & (yy==yc) & (xx==xc);
    const int noff = zc*DSTRIDE + yc*Dn + xc;
    B.m = min_[noff];
    #pragma unroll
    for (int c=0;c<16;++c) B.x[c] = xin[(size_t)c*Sn + noff];
}

__device__ __forceinline__ void accum_t(int t, const XBuf& A,
    const float* __restrict__ wpT, v2f* pv)
{
    const float mv = A.v ? A.m : 0.0f;
    const v2f mvv = {mv, mv};
    const float* wrow = wpT + t*48;
    #pragma unroll
    for (int i=0;i<8;++i){
        v2f xv = {A.x[2*i], A.x[2*i+1]};
        v2f xm = xv * mvv;                               // v_pk_mul_f32
        pv[i]    = __builtin_elementwise_fma(ld2(wrow + 2*i),      xm, pv[i]);
        pv[8+i]  = __builtin_elementwise_fma(ld2(wrow + 16 + 2*i), xm, pv[8+i]);
        pv[16+i] = __builtin_elementwise_fma(ld2(wrow + 32 + 2*i), xm, pv[16+i]);
    }
}

// fused: masked stencil dwconv (fp32 VALU) -> MLP 48->64->64->16 via SPLIT-f16
// MFMA (3-term, ~fp32 accuracy) -> residual -> unmasked x_new; ch3 atomicMax.
// ALL LDS rows are wave-private (voxel row == tid; frag rows = 64*wv+...),
// one uniform 136 B row stride everywhere -> ZERO __syncthreads in kernel.
__global__ __launch_bounds__(256, 2) void update_kernel(
    const float* __restrict__ xin, const float* __restrict__ min_,
    float* __restrict__ xout,
    const float* __restrict__ wpT, const float* __restrict__ bpP,
    const _Float16* __restrict__ w1Fh, const _Float16* __restrict__ w1Fl,
    const float* __restrict__ b1,
    const _Float16* __restrict__ w2Fh, const _Float16* __restrict__ w2Fl,
    const float* __restrict__ b2,
    const _Float16* __restrict__ w3Fh, const _Float16* __restrict__ w3Fl,
    const float* __restrict__ b3,
    unsigned* __restrict__ slot_post)
{
    __shared__ __align__(16) char smemRaw[2*256*HROW*2];  // 69632 B
    _Float16* sHi = (_Float16*)smemRaw;                  // [256][68]
    _Float16* sLo = (_Float16*)(smemRaw + 256*HROW*2);   // [256][68]
    float*    sO  = (float*)smemRaw;                     // [256][34] stride, 17 used

    const int tid = threadIdx.x;
    const int w = blockIdx.x*32 + (tid & 31);
    const int h = blockIdx.y*8  + (tid >> 5);
    const int d = blockIdx.z;
    const int idx = d*DSTRIDE + h*Dn + w;

    const int lane = tid & 63;
    const int wv   = tid >> 6;       // wave id 0..3
    const int lr   = lane & 15;      // tile row/col within fragment
    const int lg   = lane >> 4;      // k-group / row-group

    // ---------------- stencil dwconv (fp32 VALU, unchanged) ----------------
    v2f pv[24];
    #pragma unroll
    for (int j=0;j<24;++j) pv[j] = ld2(bpP + 2*j);

    XBuf A, B;
    prefetch_t(0, d, h, w, xin, min_, A);
    #pragma unroll 1
    for (int t=0; t<26; t+=2){
        prefetch_t(t+1, d, h, w, xin, min_, B);
        accum_t(t, A, wpT, pv);
        prefetch_t(t+2, d, h, w, xin, min_, A);
        accum_t(t+1, B, wpT, pv);
    }
    accum_t(26, A, wpT, pv);

    // split p -> (hi,lo) f16, store row tid (wave-private)
    {
        _Float16* pa = sHi + tid*HROW;
        _Float16* pb = sLo + tid*HROW;
        #pragma unroll
        for (int j=0;j<12;++j){
            const float f0=pv[2*j].x, f1=pv[2*j].y, f2=pv[2*j+1].x, f3=pv[2*j+1].y;
            v4h hi = {(_Float16)f0,(_Float16)f1,(_Float16)f2,(_Float16)f3};
            v4h lo = {(_Float16)(f0-(float)hi[0]), (_Float16)(f1-(float)hi[1]),
                      (_Float16)(f2-(float)hi[2]), (_Float16)(f3-(float)hi[3])};
            *(v4h*)(pa + 4*j) = hi;
            *(v4h*)(pb + 4*j) = lo;
        }
    }

    const int arow = 64*wv + lr;     // A-fragment row (voxel) base for this lane

    // ---------- GEMM1: h1 = tanh(p @ W1 + b1)  [256x48]@[48x64] ------------
    v4f acc1[4][4];
    #pragma unroll
    for (int nt=0;nt<4;++nt){
        const float bv = b1[nt*16 + lr];
        #pragma unroll
        for (int mt=0;mt<4;++mt) acc1[mt][nt] = (v4f){bv,bv,bv,bv};
    }
    #pragma unroll
    for (int ks=0;ks<3;++ks){
        v4h bh[4], bl[4];
        #pragma unroll
        for (int nt=0;nt<4;++nt){
            bh[nt] = *(const v4h*)(w1Fh + (((nt*3+ks)*64 + lane) << 2));
            bl[nt] = *(const v4h*)(w1Fl + (((nt*3+ks)*64 + lane) << 2));
        }
        #pragma unroll
        for (int mt=0;mt<4;++mt){
            const int ro = (arow + 16*mt)*HROW + ks*16 + lg*4;
            const v4h ah = *(const v4h*)(sHi + ro);
            const v4h al = *(const v4h*)(sLo + ro);
            #pragma unroll
            for (int nt=0;nt<4;++nt){
                acc1[mt][nt] = __builtin_amdgcn_mfma_f32_16x16x16f16(ah, bh[nt], acc1[mt][nt], 0,0,0);
                acc1[mt][nt] = __builtin_amdgcn_mfma_f32_16x16x16f16(al, bh[nt], acc1[mt][nt], 0,0,0);
                acc1[mt][nt] = __builtin_amdgcn_mfma_f32_16x16x16f16(ah, bl[nt], acc1[mt][nt], 0,0,0);
            }
        }
    }
    // tanh + split-scatter h1 (C-layout rows are wave-private; reads done)
    #pragma unroll
    for (int mt=0;mt<4;++mt){
        const int rbase = 64*wv + 16*mt + lg*4;
        #pragma unroll
        for (int nt=0;nt<4;++nt){
            #pragma unroll
            for (int r=0;r<4;++r){
                const float v = ftanh(acc1[mt][nt][r]);
                const _Float16 hh = (_Float16)v;
                sHi[(rbase + r)*HROW + nt*16 + lr] = hh;
                sLo[(rbase + r)*HROW + nt*16 + lr] = (_Float16)(v - (float)hh);
            }
        }
    }

    // ---------- GEMM2: h2 = tanh(h1 @ W2 + b2)  [256x64]@[64x64] -----------
    v4f acc2[4][4];
    #pragma unroll
    for (int nt=0;nt<4;++nt){
        const float bv = b2[nt*16 + lr];
        #pragma unroll
        for (int mt=0;mt<4;++mt) acc2[mt][nt] = (v4f){bv,bv,bv,bv};
    }
    #pragma unroll
    for (int ks=0;ks<4;++ks){
        v4h bh[4], bl[4];
        #pragma unroll
        for (int nt=0;nt<4;++nt){
            bh[nt] = *(const v4h*)(w2Fh + (((nt*4+ks)*64 + lane) << 2));
            bl[nt] = *(const v4h*)(w2Fl + (((nt*4+ks)*64 + lane) << 2));
        }
        #pragma unroll
        for (int mt=0;mt<4;++mt){
            const int ro = (arow + 16*mt)*HROW + ks*16 + lg*4;
            const v4h ah = *(const v4h*)(sHi + ro);
            const v4h al = *(const v4h*)(sLo + ro);
            #pragma unroll
            for (int nt=0;nt<4;++nt){
                acc2[mt][nt] = __builtin_amdgcn_mfma_f32_16x16x16f16(ah, bh[nt], acc2[mt][nt], 0,0,0);
                acc2[mt][nt] = __builtin_amdgcn_mfma_f32_16x16x16f16(al, bh[nt], acc2[mt][nt], 0,0,0);
                acc2[mt][nt] = __builtin_amdgcn_mfma_f32_16x16x16f16(ah, bl[nt], acc2[mt][nt], 0,0,0);
            }
        }
    }
    // tanh + split-scatter h2 in place (same rows, same stride)
    #pragma unroll
    for (int mt=0;mt<4;++mt){
        const int rbase = 64*wv + 16*mt + lg*4;
        #pragma unroll
        for (int nt=0;nt<4;++nt){
            #pragma unroll
            for (int r=0;r<4;++r){
                const float v = ftanh(acc2[mt][nt][r]);
                const _Float16 hh = (_Float16)v;
                sHi[(rbase + r)*HROW + nt*16 + lr] = hh;
                sLo[(rbase + r)*HROW + nt*16 + lr] = (_Float16)(v - (float)hh);
            }
        }
    }

    // ---------- GEMM3: o = h2 @ W3 + b3  [256x64]@[64x16] ------------------
    v4f acc3[4];
    {
        const float bv = b3[lr];
        #pragma unroll
        for (int mt=0;mt<4;++mt) acc3[mt] = (v4f){bv,bv,bv,bv};
    }
    #pragma unroll
    for (int ks=0;ks<4;++ks){
        const v4h bh = *(const v4h*)(w3Fh + ((ks*64 + lane) << 2));
        const v4h bl = *(const v4h*)(w3Fl + ((ks*64 + lane) << 2));
        #pragma unroll
        for (int mt=0;mt<4;++mt){
            const int ro = (arow + 16*mt)*HROW + ks*16 + lg*4;
            const v4h ah = *(const v4h*)(sHi + ro);
            const v4h al = *(const v4h*)(sLo + ro);
            acc3[mt] = __builtin_amdgcn_mfma_f32_16x16x16f16(ah, bh, acc3[mt], 0,0,0);
            acc3[mt] = __builtin_amdgcn_mfma_f32_16x16x16f16(al, bh, acc3[mt], 0,0,0);
            acc3[mt] = __builtin_amdgcn_mfma_f32_16x16x16f16(ah, bl, acc3[mt], 0,0,0);
        }
    }
    // write o rows (f32, same 136 B row stride -> wave-private, no barrier)
    #pragma unroll
    for (int mt=0;mt<4;++mt){
        const int rbase = 64*wv + 16*mt + lg*4;
        #pragma unroll
        for (int r=0;r<4;++r)
            sO[(rbase + r)*(HROW/2) + lr] = acc3[mt][r];
    }

    // ---------------- residual + store + ch3 max ---------------------------
    const float mcen = min_[idx];
    const float* orow = sO + tid*(HROW/2);
    float v3 = 0.0f;
    #pragma unroll
    for (int c=0;c<16;++c){
        const float xn = fmaf(xin[(size_t)c*Sn+idx], mcen, orow[c]);
        xout[(size_t)c*Sn+idx] = xn;
        if (c==3) v3 = xn;
    }

    #pragma unroll
    for (int o=32;o;o>>=1) v3 = fmaxf(v3, __shfl_down(v3, o));
    if ((tid & 63) == 0) atomicMax(slot_post, encf(v3));
}

// alive0 from masked old ch3, alive1 from unmasked new ch3; life mask includes
// the boundary zero x[:, :, -1, 48:, :]=0; also produces next step's pre-max
__global__ __launch_bounds__(256) void mask_kernel(
    const float* __restrict__ xin3, const float* __restrict__ min_,
    const float* __restrict__ xout3, float* __restrict__ mout,
    const unsigned* __restrict__ slot_pre, const unsigned* __restrict__ slot_post,
    unsigned* __restrict__ slot_next)
{
    const int idx = blockIdx.x*256 + threadIdx.x;
    const int w = idx % Dn;
    const int h = (idx / Dn) % Dn;
    const int d = idx / DSTRIDE;
    const float th0 = 0.1f * decf(*slot_pre);
    const float th1 = 0.1f * decf(*slot_post);
    float a0 = -INFINITY, a1 = -INFINITY;
    #pragma unroll
    for (int t=0;t<27;++t){
        const int dz=t/9-1, dy=(t/3)%3-1, dx=t%3-1;
        const int zz=d+dz, yy=h+dy, xx=w+dx;
        if ((unsigned)zz<(unsigned)Dn && (unsigned)yy<(unsigned)Dn &&
            (unsigned)xx<(unsigned)Dn){
            const int noff = idx + dz*DSTRIDE + dy*Dn + dx;
            a0 = fmaxf(a0, xin3[noff]*min_[noff]);
            a1 = fmaxf(a1, xout3[noff]);
        }
    }
    const bool life = (a0 > th0) && (a1 > th1) && !(d==Dn-1 && h>=48);
    const float mv = life ? 1.0f : 0.0f;
    mout[idx] = mv;

    float f3 = xout3[idx]*mv;   // final ch3 value -> pre-max of next step
    #pragma unroll
    for (int o=32;o;o>>=1) f3 = fmaxf(f3, __shfl_down(f3, o));
    __shared__ float red[4];
    const int lane = threadIdx.x & 63, wid = threadIdx.x >> 6;
    if (lane==0) red[wid]=f3;
    __syncthreads();
    if (threadIdx.x==0){
        float m = fmaxf(fmaxf(red[0],red[1]), fmaxf(red[2],red[3]));
        atomicMax(slot_next, encf(m));
    }
}

// final: apply last step's mask in place on d_out
__global__ __launch_bounds__(256) void apply_kernel(float* __restrict__ x,
    const float* __restrict__ mk)
{
    const int idx = blockIdx.x*256 + threadIdx.x;
    const float m = mk[idx];
    #pragma unroll
    for (int c=0;c<Cn;++c) x[(size_t)c*Sn+idx] *= m;
}

extern "C" void kernel_launch(void* const* d_in, const int* in_sizes, int n_in,
                              void* d_out, int out_size, void* d_ws, size_t ws_size,
                              hipStream_t stream)
{
    const float* x0 = (const float*)d_in[0];
    const float* wp = (const float*)d_in[1];
    const float* bp = (const float*)d_in[2];
    const float* w1 = (const float*)d_in[3];
    const float* b1 = (const float*)d_in[4];
    const float* w2 = (const float*)d_in[5];
    const float* b2 = (const float*)d_in[6];
    const float* w3 = (const float*)d_in[7];
    const float* b3 = (const float*)d_in[8];
    float* out = (float*)d_out;

    // ws: xbuf 16*Sn | maskA Sn | maskB Sn | maxv 16 u32 | wpT 1296 f |
    //     bpP 48 f | split-f16 weight frags (16384 h = 32 KB)
    float* xbuf  = (float*)d_ws;
    float* maskA = xbuf + (size_t)Cn*Sn;
    float* maskB = maskA + Sn;
    unsigned* maxv = (unsigned*)(maskB + Sn);
    float* wpT = (float*)(maxv + 16);
    float* bpP = wpT + 1296;
    _Float16* w1Fh = (_Float16*)(bpP + 48);
    _Float16* w1Fl = w1Fh + 3072;
    _Float16* w2Fh = w1Fl + 3072;
    _Float16* w2Fl = w2Fh + 4096;
    _Float16* w3Fh = w2Fl + 4096;
    _Float16* w3Fl = w3Fh + 1024;

    init_kernel<<<1, 64, 0, stream>>>(maxv);
    tr_kernel<<<6, 256, 0, stream>>>(wp, bp, wpT, bpP);
    pack_kernel<<<16, 256, 0, stream>>>(w1, w2, w3, w1Fh, w1Fl, w2Fh, w2Fl, w3Fh, w3Fl);
    prep_kernel<<<Sn/256, 256, 0, stream>>>(x0 + (size_t)3*Sn, maskA, &maxv[0]);

    // ping-pong unmasked x_new between ws buffer and d_out; masks alternate A/B
    const float* xi[4] = {x0,   xbuf, out,  xbuf};
    float*       xo[4] = {xbuf, out,  xbuf, out};
    const float* mi[4] = {maskA, maskB, maskA, maskB};
    float*       mo[4] = {maskB, maskA, maskB, maskA};

    dim3 ugrid(Dn/32, Dn/8, Dn);
    for (int s=0; s<4; ++s){
        update_kernel<<<ugrid, 256, 0, stream>>>(xi[s], mi[s], xo[s],
            wpT, bpP, w1Fh, w1Fl, b1, w2Fh, w2Fl, b2, w3Fh, w3Fl, b3, &maxv[2*s+1]);
        mask_kernel<<<Sn/256, 256, 0, stream>>>(xi[s]+(size_t)3*Sn, mi[s],
            xo[s]+(size_t)3*Sn, mo[s], &maxv[2*s], &maxv[2*s+1], &maxv[2*s+2]);
    }
    apply_kernel<<<Sn/256, 256, 0, stream>>>(out, maskA);
}